// Round 2
// baseline (13847.069 us; speedup 1.0000x reference)
//
#include <hip/hip_runtime.h>

// VQC 16-wire / 10-layer statevector simulator — single fused kernel.
//
// One batch per block (128 blocks x 1024 threads). Global amp index g:
//   normal mapping:     g[15:6] = tid[9:0], g[5:0] = j (64 complex amps/thread)
//   transposed mapping: g[15:12]=j[5:2], g[11:6]=tid[5:0], g[5:2]=tid[9:6], g[1:0]=j[1:0]
// Wire w <-> bit 15-w. Per layer, all 9 CNOTs fold into the rotation on their
// target wire as a conditional column swap (verified order from round 1):
//   [T] R1 R0 R15 R14 R3 R2 [T^-1] R5 R4 R7 R6 R9 R8 R11 R10 R13 R12
// The LDS transpose T (swap g[15:12]<->g[5:2], an involution) makes wires 0..3
// register-local so the whole layer needs only 2 LDS passes. State never
// touches HBM between layers.

#define NW 16
#define NL 10
#define NB 128

__global__ void coef_kernel(const float* __restrict__ params, float4* __restrict__ cf) {
    int idx = blockIdx.x * blockDim.x + threadIdx.x;
    if (idx >= NB * NL * NW) return;
    int wire  = idx & 15;
    int layer = (idx >> 4) % NL;
    int batch = idx / (NW * NL);
    const float* p = params + batch * (3 * NW * NL) + layer * (3 * NW) + wire * 3;
    float sx, cx, sy, cy, sz, cz;
    sincosf(0.5f * p[0], &sx, &cx);
    sincosf(0.5f * p[1], &sy, &cy);
    sincosf(0.5f * p[2], &sz, &cz);
    // U = RZ(tz) RY(ty) RX(tx);  u10 = -conj(u01), u11 = conj(u00).
    float4 o;
    o.x =  cz * cy * cx + sz * sy * sx;   // u00.re
    o.y =  cz * sy * sx - sz * cy * cx;   // u00.im
    o.z = -cz * sy * cx - sz * cy * sx;   // u01.re
    o.w = -cz * cy * sx + sz * sy * cx;   // u01.im
    cf[idx] = o;
}

__device__ __forceinline__ float2 cmul2(float2 a, float2 b) {
    return make_float2(a.x * b.x - a.y * b.y, a.x * b.y + a.y * b.x);
}

// one-sided coeff select: co = U[r][r^c], cp = U[r][(1-r)^c]
__device__ __forceinline__ void osel(float2 u00, float2 u01, float2 u10, float2 u11,
                                     int r, int cond, float2& co, float2& cp) {
    float2 a = r ? u10 : u00;  // U[r][0]
    float2 b = r ? u11 : u01;  // U[r][1]
    bool k = ((r ^ cond) & 1) != 0;
    co = k ? b : a;
    cp = k ? a : b;
}

__global__ __launch_bounds__(1024) void vqc_all(const float4* __restrict__ cf,
                                                float* __restrict__ out) {
    __shared__ float ldsr[1024 * 17];
    __shared__ float ldsi[1024 * 17];
    const int b   = blockIdx.x;
    const int tid = threadIdx.x;
    const float4* cfb = cf + b * (NL * NW);

    float sr[64], si[64];

#define LOADU(LAY, WIRE)                              \
    float2 u00, u01, u10, u11;                        \
    {                                                 \
        float4 c = cfb[(LAY) * NW + (WIRE)];          \
        u00 = make_float2(c.x, c.y);                  \
        u01 = make_float2(c.z, c.w);                  \
        u10 = make_float2(-c.z, c.w);                 \
        u11 = make_float2(c.x, -c.y);                 \
    }

    // two-sided register-pair gate on j-bit K; CONDEXPR may reference jA (compile-time)
#define REG_GATE(LAY, WIRE, K, CONDEXPR)                                       \
    {                                                                          \
        LOADU(LAY, WIRE);                                                      \
        _Pragma("unroll")                                                      \
        for (int p = 0; p < 32; ++p) {                                         \
            const int jA = ((p >> (K)) << ((K) + 1)) | (p & ((1 << (K)) - 1)); \
            const int jB = jA | (1 << (K));                                    \
            const bool c = (CONDEXPR) != 0;                                    \
            float2 a0 = c ? u01 : u00, a1 = c ? u00 : u01;                     \
            float2 b0 = c ? u11 : u10, b1 = c ? u10 : u11;                     \
            float ar = sr[jA], ai = si[jA], br = sr[jB], bi = si[jB];          \
            sr[jA] = a0.x * ar - a0.y * ai + a1.x * br - a1.y * bi;            \
            si[jA] = a0.x * ai + a0.y * ar + a1.x * bi + a1.y * br;            \
            sr[jB] = b0.x * ar - b0.y * ai + b1.x * br - b1.y * bi;            \
            si[jB] = b0.x * ai + b0.y * ar + b1.x * bi + b1.y * br;            \
        }                                                                      \
    }

    // one-sided shuffle gate on lane-bit mask MASK; r = tid[RBIT], cond uniform
#define SHFL_GATE(LAY, WIRE, MASK, RBIT, CONDVAL)                         \
    {                                                                     \
        LOADU(LAY, WIRE);                                                 \
        float2 co, cp;                                                    \
        osel(u00, u01, u10, u11, (tid >> (RBIT)) & 1, (CONDVAL), co, cp); \
        _Pragma("unroll")                                                 \
        for (int j = 0; j < 64; ++j) {                                    \
            float pr = __shfl_xor(sr[j], (MASK), 64);                     \
            float pi = __shfl_xor(si[j], (MASK), 64);                     \
            float a_ = sr[j], b_ = si[j];                                 \
            sr[j] = co.x * a_ - co.y * b_ + cp.x * pr - cp.y * pi;        \
            si[j] = co.x * b_ + co.y * a_ + cp.x * pi + cp.y * pr;        \
        }                                                                 \
    }

    // involutive ownership transpose: swap g[15:12] <-> g[5:2].
    // Chunked by q = j[1:0]; stride-17 float planes -> conflict-free.
#define TRANSPOSE()                                                 \
    {                                                               \
        const int lane6 = tid & 63;                                 \
        const int hi4   = tid >> 6;                                 \
        _Pragma("unroll")                                           \
        for (int q = 0; q < 4; ++q) {                               \
            __syncthreads();                                        \
            _Pragma("unroll")                                       \
            for (int s = 0; s < 16; ++s) {                          \
                ldsr[tid * 17 + s] = sr[s * 4 + q];                 \
                ldsi[tid * 17 + s] = si[s * 4 + q];                 \
            }                                                       \
            __syncthreads();                                        \
            _Pragma("unroll")                                       \
            for (int s = 0; s < 16; ++s) {                          \
                const int addr = ((s << 6) | lane6) * 17 + hi4;     \
                sr[s * 4 + q] = ldsr[addr];                         \
                si[s * 4 + q] = ldsi[addr];                         \
            }                                                       \
        }                                                           \
    }

    // ---- layer 0: CNOTs identity on |0>, state = product of U[:, bit] columns ----
    {
        float2 P = make_float2(1.f, 0.f);
#pragma unroll
        for (int w = 0; w < 10; ++w) {
            LOADU(0, w);
            int bit = (tid >> (9 - w)) & 1;
            P = cmul2(P, bit ? u10 : u00);
        }
        float2 f0[6], f1[6];
#pragma unroll
        for (int i = 0; i < 6; ++i) {
            LOADU(0, 10 + i);
            f0[i] = u00;
            f1[i] = u10;
        }
        float2 thi[8], tlo[8];
#pragma unroll
        for (int h = 0; h < 8; ++h) {
            float2 x = (h & 4) ? f1[0] : f0[0];           // wire 10 <- j[5]
            x = cmul2(x, (h & 2) ? f1[1] : f0[1]);        // wire 11 <- j[4]
            x = cmul2(x, (h & 1) ? f1[2] : f0[2]);        // wire 12 <- j[3]
            thi[h] = x;
            float2 y = (h & 4) ? f1[3] : f0[3];           // wire 13 <- j[2]
            y = cmul2(y, (h & 2) ? f1[4] : f0[4]);        // wire 14 <- j[1]
            y = cmul2(y, (h & 1) ? f1[5] : f0[5]);        // wire 15 <- j[0]
            tlo[h] = y;
        }
#pragma unroll
        for (int j = 0; j < 64; ++j) {
            float2 a = cmul2(P, cmul2(thi[j >> 3], tlo[j & 7]));
            sr[j] = a.x;
            si[j] = a.y;
        }
    }

    // ---- layers 1..9 ----
#pragma unroll 1
    for (int L = 1; L < NL; ++L) {
        TRANSPOSE();
        // transposed mapping: wire0=j[5], wire1=j[4], wire2=j[3], wire3=j[2],
        //                     wire14=j[1], wire15=j[0]
        REG_GATE(L, 1, 4, (jA >> 5) & 1);         // R1, cond wire0      [CN(0,1)]
        REG_GATE(L, 0, 5, (jA ^ (jA >> 1)) & 1);  // R0, cond w15^w14    [CN(15,0)]
        REG_GATE(L, 15, 0, (jA >> 1) & 1);        // R15, cond wire14    [CN(14,15)]
        REG_GATE(L, 14, 1, 0);                    // R14
        REG_GATE(L, 3, 2, (jA >> 3) & 1);         // R3, cond wire2      [CN(2,3)]
        REG_GATE(L, 2, 3, 0);                     // R2
        TRANSPOSE();
        // normal mapping: wire4=tid[5], wire5=tid[4], ..., wire9=tid[0],
        //                 wire10=j[5], ..., wire15=j[0]
        SHFL_GATE(L, 5, 16, 4, (tid >> 5) & 1);   // R5, cond wire4      [CN(4,5)]
        SHFL_GATE(L, 4, 32, 5, 0);                // R4
        SHFL_GATE(L, 7, 4, 2, (tid >> 3) & 1);    // R7, cond wire6      [CN(6,7)]
        SHFL_GATE(L, 6, 8, 3, 0);                 // R6
        SHFL_GATE(L, 9, 1, 0, (tid >> 1) & 1);    // R9, cond wire8      [CN(8,9)]
        SHFL_GATE(L, 8, 2, 1, 0);                 // R8
        REG_GATE(L, 11, 4, (jA >> 5) & 1);        // R11, cond wire10    [CN(10,11)]
        REG_GATE(L, 10, 5, 0);                    // R10
        REG_GATE(L, 13, 2, (jA >> 3) & 1);        // R13, cond wire12    [CN(12,13)]
        REG_GATE(L, 12, 3, 0);                    // R12
    }

    // ---- probabilities ----
    {
        float4* o4 = (float4*)(out + (((size_t)b << 16) | (size_t)(tid << 6)));
#pragma unroll
        for (int k = 0; k < 16; ++k) {
            float4 v;
            v.x = sr[4 * k + 0] * sr[4 * k + 0] + si[4 * k + 0] * si[4 * k + 0];
            v.y = sr[4 * k + 1] * sr[4 * k + 1] + si[4 * k + 1] * si[4 * k + 1];
            v.z = sr[4 * k + 2] * sr[4 * k + 2] + si[4 * k + 2] * si[4 * k + 2];
            v.w = sr[4 * k + 3] * sr[4 * k + 3] + si[4 * k + 3] * si[4 * k + 3];
            o4[k] = v;
        }
    }
#undef LOADU
#undef REG_GATE
#undef SHFL_GATE
#undef TRANSPOSE
}

extern "C" void kernel_launch(void* const* d_in, const int* in_sizes, int n_in,
                              void* d_out, int out_size, void* d_ws, size_t ws_size,
                              hipStream_t stream) {
    const float* params = (const float*)d_in[0];
    float* out = (float*)d_out;
    float4* cf = (float4*)d_ws;  // 128*160 float4 = 320 KiB gate coefficients

    coef_kernel<<<80, 256, 0, stream>>>(params, cf);
    vqc_all<<<NB, 1024, 0, stream>>>(cf, out);
}

// Round 3
// 1077.475 us; speedup vs baseline: 12.8514x; 12.8514x over previous
//
#include <hip/hip_runtime.h>
#include <hip/hip_cooperative_groups.h>

namespace cg = cooperative_groups;

// VQC 16-wire / 10-layer statevector simulator — single cooperative kernel.
//
// 256 blocks x 1024 threads, 2 blocks per batch (bb = blockIdx>>1, h = blockIdx&1).
// Normal mapping:     g[15]=h, g[14:5]=tid[9:0], g[4:0]=j   (32 complex/thread, 64 VGPRs)
// Transposed mapping: T swaps g[14:11]<->g[4:1] (tid[9:6]<->j[4:1]), involution via LDS.
// Wire w <-> bit 15-w. Verified per-layer gate order (rounds 1-2, absmax 3e-5):
//   R1 R0 R15 R14 R3 R2 R5 R4 R7 R6 R9 R8 R11 R10 R13 R12
// with R1(L+1) commuted ahead of R11 R10 R13 R12 (disjoint wire supports).
// Wire 0 (bit15) is cross-block: store own half, grid.sync(), load partner half
// fused into R0. State stays in registers the whole circuit (launch_bounds(1024,4)
// -> 128-VGPR cap, no spill).

#define NW 16
#define NL 10
#define NB 128

__global__ void coef_kernel(const float* __restrict__ params, float4* __restrict__ cf) {
    int idx = blockIdx.x * blockDim.x + threadIdx.x;
    if (idx >= NB * NL * NW) return;
    int wire  = idx & 15;
    int layer = (idx >> 4) % NL;
    int batch = idx / (NW * NL);
    const float* p = params + batch * (3 * NW * NL) + layer * (3 * NW) + wire * 3;
    float sx, cx, sy, cy, sz, cz;
    sincosf(0.5f * p[0], &sx, &cx);
    sincosf(0.5f * p[1], &sy, &cy);
    sincosf(0.5f * p[2], &sz, &cz);
    // U = RZ(tz) RY(ty) RX(tx);  u10 = -conj(u01), u11 = conj(u00).
    float4 o;
    o.x =  cz * cy * cx + sz * sy * sx;   // u00.re
    o.y =  cz * sy * sx - sz * cy * cx;   // u00.im
    o.z = -cz * sy * cx - sz * cy * sx;   // u01.re
    o.w = -cz * cy * sx + sz * sy * cx;   // u01.im
    cf[idx] = o;
}

__device__ __forceinline__ float2 cmul2(float2 a, float2 b) {
    return make_float2(a.x * b.x - a.y * b.y, a.x * b.y + a.y * b.x);
}

// one-sided coeff select: co = U[r][r^c], cp = U[r][(1-r)^c]
__device__ __forceinline__ void osel(float2 u00, float2 u01, float2 u10, float2 u11,
                                     int r, int cond, float2& co, float2& cp) {
    float2 a = r ? u10 : u00;  // U[r][0]
    float2 b = r ? u11 : u01;  // U[r][1]
    bool k = ((r ^ cond) & 1) != 0;
    co = k ? b : a;
    cp = k ? a : b;
}

__global__ __launch_bounds__(1024, 4) void vqc_coop(const float4* __restrict__ cf,
                                                    float2* __restrict__ buf0,
                                                    float2* __restrict__ buf1,
                                                    float* __restrict__ out) {
    __shared__ float ldsr[1024 * 17];
    __shared__ float ldsi[1024 * 17];
    cg::grid_group grid = cg::this_grid();
    const int bb  = blockIdx.x >> 1;
    const int h   = blockIdx.x & 1;
    const int tid = threadIdx.x;
    const float4* cfb = cf + bb * (NL * NW);

    float sr[32], si[32];

#define LOADU(LAY, WIRE)                              \
    float2 u00, u01, u10, u11;                        \
    {                                                 \
        float4 c = cfb[(LAY) * NW + (WIRE)];          \
        u00 = make_float2(c.x, c.y);                  \
        u01 = make_float2(c.z, c.w);                  \
        u10 = make_float2(-c.z, c.w);                 \
        u11 = make_float2(c.x, -c.y);                 \
    }

    // two-sided register-pair gate on j-bit K; CONDEXPR may use jA (compile-time)
    // or runtime-uniform values (h, tid bits).
#define REG_GATE(LAY, WIRE, K, CONDEXPR)                                        \
    {                                                                           \
        LOADU(LAY, WIRE);                                                       \
        _Pragma("unroll")                                                       \
        for (int p_ = 0; p_ < 16; ++p_) {                                       \
            const int jA = ((p_ >> (K)) << ((K) + 1)) | (p_ & ((1 << (K)) - 1));\
            const int jB = jA | (1 << (K));                                     \
            const bool c = (CONDEXPR) != 0;                                     \
            float2 a0 = c ? u01 : u00, a1 = c ? u00 : u01;                      \
            float2 b0 = c ? u11 : u10, b1 = c ? u10 : u11;                      \
            float ar = sr[jA], ai = si[jA], br = sr[jB], bi = si[jB];           \
            sr[jA] = a0.x * ar - a0.y * ai + a1.x * br - a1.y * bi;             \
            si[jA] = a0.x * ai + a0.y * ar + a1.x * bi + a1.y * br;             \
            sr[jB] = b0.x * ar - b0.y * ai + b1.x * br - b1.y * bi;             \
            si[jB] = b0.x * ai + b0.y * ar + b1.x * bi + b1.y * br;             \
        }                                                                       \
    }

    // one-sided shuffle gate on lane-bit MASK; r = tid[RBIT], uniform cond.
#define SHFL_GATE(LAY, WIRE, MASK, RBIT, CONDVAL)                         \
    {                                                                     \
        LOADU(LAY, WIRE);                                                 \
        float2 co, cp;                                                    \
        osel(u00, u01, u10, u11, (tid >> (RBIT)) & 1, (CONDVAL), co, cp); \
        _Pragma("unroll")                                                 \
        for (int j = 0; j < 32; ++j) {                                    \
            float pr = __shfl_xor(sr[j], (MASK), 64);                     \
            float pi = __shfl_xor(si[j], (MASK), 64);                     \
            float a_ = sr[j], b_ = si[j];                                 \
            sr[j] = co.x * a_ - co.y * b_ + cp.x * pr - cp.y * pi;        \
            si[j] = co.x * b_ + co.y * a_ + cp.x * pi + cp.y * pr;        \
        }                                                                 \
    }

    // shuffle gate with per-j compile-time cond (bit CB of j): c=1 swaps co/cp.
#define SHFL_GATE_J(LAY, WIRE, MASK, RBIT, CB)                        \
    {                                                                 \
        LOADU(LAY, WIRE);                                             \
        float2 co, cp;                                                \
        osel(u00, u01, u10, u11, (tid >> (RBIT)) & 1, 0, co, cp);     \
        _Pragma("unroll")                                             \
        for (int j = 0; j < 32; ++j) {                                \
            float pr = __shfl_xor(sr[j], (MASK), 64);                 \
            float pi = __shfl_xor(si[j], (MASK), 64);                 \
            const bool c = ((j >> (CB)) & 1) != 0;                    \
            float2 x = c ? cp : co, y = c ? co : cp;                  \
            float a_ = sr[j], b_ = si[j];                             \
            sr[j] = x.x * a_ - x.y * b_ + y.x * pr - y.y * pi;        \
            si[j] = x.x * b_ + x.y * a_ + y.x * pi + y.y * pr;        \
        }                                                             \
    }

    // involutive ownership transpose: swap tid[9:6] <-> j[4:1] via LDS.
    // j = (s<<1)|q; stride-17 planes -> 2-way bank aliasing only (free).
#define TRANSPOSE()                                                  \
    {                                                                \
        const int lane6 = tid & 63;                                  \
        const int hi4   = tid >> 6;                                  \
        _Pragma("unroll")                                            \
        for (int q = 0; q < 2; ++q) {                                \
            __syncthreads();                                         \
            _Pragma("unroll")                                        \
            for (int s = 0; s < 16; ++s) {                           \
                ldsr[tid * 17 + s] = sr[s * 2 + q];                  \
                ldsi[tid * 17 + s] = si[s * 2 + q];                  \
            }                                                        \
            __syncthreads();                                         \
            _Pragma("unroll")                                        \
            for (int s = 0; s < 16; ++s) {                           \
                const int a_ = ((s << 6) | lane6) * 17 + hi4;        \
                sr[s * 2 + q] = ldsr[a_];                            \
                si[s * 2 + q] = ldsi[a_];                            \
            }                                                        \
        }                                                            \
    }

    // ---- layer 0 (analytic, in TRANSPOSED mapping) ----
    // transposed bits: wire0:h, wire1:j4, wire2:j3, wire3:j2, wire4:j1, wire15:j0,
    // wire5..10: tid5..tid0, wire11..14: tid9..tid6.
    {
        float2 P = make_float2(1.f, 0.f);
        {
            LOADU(0, 0);
            P = cmul2(P, h ? u10 : u00);
        }
#pragma unroll
        for (int w = 5; w <= 10; ++w) {
            LOADU(0, w);
            int bit = (tid >> (10 - w)) & 1;
            P = cmul2(P, bit ? u10 : u00);
        }
#pragma unroll
        for (int w = 11; w <= 14; ++w) {
            LOADU(0, w);
            int bit = (tid >> (20 - w)) & 1;
            P = cmul2(P, bit ? u10 : u00);
        }
        float2 fA0[3], fA1[3];  // wires 1,2,3 <- j4,j3,j2
        float2 fB0[2], fB1[2];  // wires 4,15 <- j1,j0
#pragma unroll
        for (int i = 0; i < 3; ++i) {
            LOADU(0, 1 + i);
            fA0[i] = u00; fA1[i] = u10;
        }
        {
            LOADU(0, 4);
            fB0[0] = u00; fB1[0] = u10;
        }
        {
            LOADU(0, 15);
            fB0[1] = u00; fB1[1] = u10;
        }
        float2 A[8], Bt[4];
#pragma unroll
        for (int a = 0; a < 8; ++a) {
            float2 x = (a & 4) ? fA1[0] : fA0[0];
            x = cmul2(x, (a & 2) ? fA1[1] : fA0[1]);
            x = cmul2(x, (a & 1) ? fA1[2] : fA0[2]);
            A[a] = cmul2(P, x);
        }
#pragma unroll
        for (int b2 = 0; b2 < 4; ++b2) {
            float2 y = (b2 & 2) ? fB1[0] : fB0[0];
            y = cmul2(y, (b2 & 1) ? fB1[1] : fB0[1]);
            Bt[b2] = y;
        }
#pragma unroll
        for (int j = 0; j < 32; ++j) {
            float2 a = cmul2(A[j >> 2], Bt[j & 3]);
            sr[j] = a.x;
            si[j] = a.y;
        }
    }
    // R1(layer 1): transposed reg gate on j4 (wire1), cond wire0 = h  [CN(0,1)]
    REG_GATE(1, 1, 4, h);
    TRANSPOSE();  // -> normal mapping

    // ---- layers 1..9 ----
#pragma unroll 1
    for (int L = 1; L < NL; ++L) {
        float2* bufp = (L & 1) ? buf0 : buf1;
        // store own half (state = post-R1(L)), normal mapping
        {
            float4* wb = (float4*)(bufp + (((size_t)bb << 16) | ((size_t)h << 15) |
                                           ((size_t)tid << 5)));
#pragma unroll
            for (int k = 0; k < 16; ++k)
                wb[k] = make_float4(sr[2 * k], si[2 * k], sr[2 * k + 1], si[2 * k + 1]);
        }
        grid.sync();
        // load partner half + R0(L): co=U[h][h], cp=U[h][1-h], cond j0^j1 [CN(15,0)]
        {
            const float4* rb = (const float4*)(bufp + (((size_t)bb << 16) |
                                                       ((size_t)(1 - h) << 15) |
                                                       ((size_t)tid << 5)));
            LOADU(L, 0);
            float2 co = h ? u11 : u00;
            float2 cp = h ? u10 : u01;
#pragma unroll
            for (int k = 0; k < 16; ++k) {
                float4 v = rb[k];
                {
                    const int j = 2 * k;
                    const bool c = ((j ^ (j >> 1)) & 1) != 0;
                    float2 x = c ? cp : co, y = c ? co : cp;
                    float a_ = sr[j], b_ = si[j];
                    sr[j] = x.x * a_ - x.y * b_ + y.x * v.x - y.y * v.y;
                    si[j] = x.x * b_ + x.y * a_ + y.x * v.y + y.y * v.x;
                }
                {
                    const int j = 2 * k + 1;
                    const bool c = ((j ^ (j >> 1)) & 1) != 0;
                    float2 x = c ? cp : co, y = c ? co : cp;
                    float a_ = sr[j], b_ = si[j];
                    sr[j] = x.x * a_ - x.y * b_ + y.x * v.z - y.y * v.w;
                    si[j] = x.x * b_ + x.y * a_ + y.x * v.w + y.y * v.z;
                }
            }
        }
        // normal mapping: wire15=j0, wire14=j1
        REG_GATE(L, 15, 0, (jA >> 1) & 1);  // R15, cond wire14   [CN(14,15)]
        REG_GATE(L, 14, 1, 0);              // R14
        TRANSPOSE();  // -> transposed
        REG_GATE(L, 3, 2, (jA >> 3) & 1);   // R3, cond wire2=j3' [CN(2,3)]
        REG_GATE(L, 2, 3, 0);               // R2
        SHFL_GATE_J(L, 5, 32, 5, 1);        // R5, cond wire4=j1' [CN(4,5)]
        REG_GATE(L, 4, 1, 0);               // R4 (reg in transposed)
        SHFL_GATE(L, 7, 8, 3, (tid >> 4) & 1);  // R7, cond wire6  [CN(6,7)]
        SHFL_GATE(L, 6, 16, 4, 0);              // R6
        SHFL_GATE(L, 9, 2, 1, (tid >> 2) & 1);  // R9, cond wire8  [CN(8,9)]
        SHFL_GATE(L, 8, 4, 2, 0);               // R8
        if (L + 1 < NL) {
            REG_GATE(L + 1, 1, 4, h);       // R1(L+1), cond wire0=h [CN(0,1)]
        }
        TRANSPOSE();  // -> normal
        REG_GATE(L, 11, 4, tid & 1);        // R11, cond wire10=tid0 [CN(10,11)]
        SHFL_GATE(L, 10, 1, 0, 0);          // R10
        REG_GATE(L, 13, 2, (jA >> 3) & 1);  // R13, cond wire12=j3   [CN(12,13)]
        REG_GATE(L, 12, 3, 0);              // R12
    }

    // ---- probabilities ----
    {
        float4* o4 = (float4*)(out + (((size_t)bb << 16) | ((size_t)h << 15) |
                                      ((size_t)tid << 5)));
#pragma unroll
        for (int k = 0; k < 8; ++k) {
            float4 v;
            v.x = sr[4 * k + 0] * sr[4 * k + 0] + si[4 * k + 0] * si[4 * k + 0];
            v.y = sr[4 * k + 1] * sr[4 * k + 1] + si[4 * k + 1] * si[4 * k + 1];
            v.z = sr[4 * k + 2] * sr[4 * k + 2] + si[4 * k + 2] * si[4 * k + 2];
            v.w = sr[4 * k + 3] * sr[4 * k + 3] + si[4 * k + 3] * si[4 * k + 3];
            o4[k] = v;
        }
    }
#undef LOADU
#undef REG_GATE
#undef SHFL_GATE
#undef SHFL_GATE_J
#undef TRANSPOSE
}

extern "C" void kernel_launch(void* const* d_in, const int* in_sizes, int n_in,
                              void* d_out, int out_size, void* d_ws, size_t ws_size,
                              hipStream_t stream) {
    const float* params = (const float*)d_in[0];
    float* out = (float*)d_out;
    char* w = (char*)d_ws;
    float2* buf0 = (float2*)w;                   // 64 MiB
    float2* buf1 = (float2*)(w + (1ULL << 26));  // 64 MiB
    float4* cf   = (float4*)(w + (1ULL << 27));  // 320 KiB gate coefficients

    coef_kernel<<<80, 256, 0, stream>>>(params, cf);

    void* args[] = {(void*)&cf, (void*)&buf0, (void*)&buf1, (void*)&out};
    hipLaunchCooperativeKernel((const void*)vqc_coop, dim3(256), dim3(1024),
                               args, 0, stream);
}

// Round 4
// 1077.404 us; speedup vs baseline: 12.8523x; 1.0001x over previous
//
#include <hip/hip_runtime.h>
#include <hip/hip_cooperative_groups.h>

namespace cg = cooperative_groups;

// VQC 16-wire / 10-layer statevector simulator — single cooperative kernel.
//
// 256 blocks x 1024 threads, 2 blocks per batch (bb = blockIdx>>1, h = blockIdx&1).
// Normal mapping:     g[15]=h, g[14:5]=tid[9:0], g[4:0]=j   (32 complex/thread, 64 VGPRs)
// Transposed mapping: T swaps g[14:11]<->g[4:1] (tid[9:6]<->j[4:1]), involution via LDS.
// Wire w <-> bit 15-w. Verified per-layer gate order (rounds 1-3, absmax 3e-5):
//   R1 R0 R15 R14 R3 R2 R5 R4 R7 R6 R9 R8 R11 R10 R13 R12
// with R1(L+1) commuted ahead of R11 R10 R13 R12 (disjoint wire supports).
// Wire 0 (bit15) is cross-block: store own half, grid.sync(), load partner half
// fused into R0.
//
// Register budget: 1024-thr workgroup = 16 waves = 4 waves/SIMD -> HW VGPR cap 128.
// __launch_bounds__(1024,4) did NOT raise the allocator cap (round 3: VGPR=64,
// state spilled to scratch, 1.4 GB excess HBM traffic). Force it with explicit
// amdgpu_waves_per_eu(4,4): budget = 512/4 = 128 VGPRs, no occupancy-chasing.

#define NW 16
#define NL 10
#define NB 128

__global__ void coef_kernel(const float* __restrict__ params, float4* __restrict__ cf) {
    int idx = blockIdx.x * blockDim.x + threadIdx.x;
    if (idx >= NB * NL * NW) return;
    int wire  = idx & 15;
    int layer = (idx >> 4) % NL;
    int batch = idx / (NW * NL);
    const float* p = params + batch * (3 * NW * NL) + layer * (3 * NW) + wire * 3;
    float sx, cx, sy, cy, sz, cz;
    sincosf(0.5f * p[0], &sx, &cx);
    sincosf(0.5f * p[1], &sy, &cy);
    sincosf(0.5f * p[2], &sz, &cz);
    // U = RZ(tz) RY(ty) RX(tx);  u10 = -conj(u01), u11 = conj(u00).
    float4 o;
    o.x =  cz * cy * cx + sz * sy * sx;   // u00.re
    o.y =  cz * sy * sx - sz * cy * cx;   // u00.im
    o.z = -cz * sy * cx - sz * cy * sx;   // u01.re
    o.w = -cz * cy * sx + sz * sy * cx;   // u01.im
    cf[idx] = o;
}

__device__ __forceinline__ float2 cmul2(float2 a, float2 b) {
    return make_float2(a.x * b.x - a.y * b.y, a.x * b.y + a.y * b.x);
}

// one-sided coeff select: co = U[r][r^c], cp = U[r][(1-r)^c]
__device__ __forceinline__ void osel(float2 u00, float2 u01, float2 u10, float2 u11,
                                     int r, int cond, float2& co, float2& cp) {
    float2 a = r ? u10 : u00;  // U[r][0]
    float2 b = r ? u11 : u01;  // U[r][1]
    bool k = ((r ^ cond) & 1) != 0;
    co = k ? b : a;
    cp = k ? a : b;
}

__global__
__attribute__((amdgpu_flat_work_group_size(1024, 1024), amdgpu_waves_per_eu(4, 4)))
void vqc_coop(const float4* __restrict__ cf,
              float2* __restrict__ buf0,
              float2* __restrict__ buf1,
              float* __restrict__ out) {
    __shared__ float ldsr[1024 * 17];
    __shared__ float ldsi[1024 * 17];
    cg::grid_group grid = cg::this_grid();
    const int bb  = blockIdx.x >> 1;
    const int h   = blockIdx.x & 1;
    const int tid = threadIdx.x;
    const float4* cfb = cf + bb * (NL * NW);

    float sr[32], si[32];

#define LOADU(LAY, WIRE)                              \
    float2 u00, u01, u10, u11;                        \
    {                                                 \
        float4 c = cfb[(LAY) * NW + (WIRE)];          \
        u00 = make_float2(c.x, c.y);                  \
        u01 = make_float2(c.z, c.w);                  \
        u10 = make_float2(-c.z, c.w);                 \
        u11 = make_float2(c.x, -c.y);                 \
    }

    // two-sided register-pair gate on j-bit K; CONDEXPR may use jA (compile-time)
    // or runtime-uniform values (h, tid bits).
#define REG_GATE(LAY, WIRE, K, CONDEXPR)                                        \
    {                                                                           \
        LOADU(LAY, WIRE);                                                       \
        _Pragma("unroll")                                                       \
        for (int p_ = 0; p_ < 16; ++p_) {                                       \
            const int jA = ((p_ >> (K)) << ((K) + 1)) | (p_ & ((1 << (K)) - 1));\
            const int jB = jA | (1 << (K));                                     \
            const bool c = (CONDEXPR) != 0;                                     \
            float2 a0 = c ? u01 : u00, a1 = c ? u00 : u01;                      \
            float2 b0 = c ? u11 : u10, b1 = c ? u10 : u11;                      \
            float ar = sr[jA], ai = si[jA], br = sr[jB], bi = si[jB];           \
            sr[jA] = a0.x * ar - a0.y * ai + a1.x * br - a1.y * bi;             \
            si[jA] = a0.x * ai + a0.y * ar + a1.x * bi + a1.y * br;             \
            sr[jB] = b0.x * ar - b0.y * ai + b1.x * br - b1.y * bi;             \
            si[jB] = b0.x * ai + b0.y * ar + b1.x * bi + b1.y * br;             \
        }                                                                       \
    }

    // one-sided shuffle gate on lane-bit MASK; r = tid[RBIT], uniform cond.
#define SHFL_GATE(LAY, WIRE, MASK, RBIT, CONDVAL)                         \
    {                                                                     \
        LOADU(LAY, WIRE);                                                 \
        float2 co, cp;                                                    \
        osel(u00, u01, u10, u11, (tid >> (RBIT)) & 1, (CONDVAL), co, cp); \
        _Pragma("unroll")                                                 \
        for (int j = 0; j < 32; ++j) {                                    \
            float pr = __shfl_xor(sr[j], (MASK), 64);                     \
            float pi = __shfl_xor(si[j], (MASK), 64);                     \
            float a_ = sr[j], b_ = si[j];                                 \
            sr[j] = co.x * a_ - co.y * b_ + cp.x * pr - cp.y * pi;        \
            si[j] = co.x * b_ + co.y * a_ + cp.x * pi + cp.y * pr;        \
        }                                                                 \
    }

    // shuffle gate with per-j compile-time cond (bit CB of j): c=1 swaps co/cp.
#define SHFL_GATE_J(LAY, WIRE, MASK, RBIT, CB)                        \
    {                                                                 \
        LOADU(LAY, WIRE);                                             \
        float2 co, cp;                                                \
        osel(u00, u01, u10, u11, (tid >> (RBIT)) & 1, 0, co, cp);     \
        _Pragma("unroll")                                             \
        for (int j = 0; j < 32; ++j) {                                \
            float pr = __shfl_xor(sr[j], (MASK), 64);                 \
            float pi = __shfl_xor(si[j], (MASK), 64);                 \
            const bool c = ((j >> (CB)) & 1) != 0;                    \
            float2 x = c ? cp : co, y = c ? co : cp;                  \
            float a_ = sr[j], b_ = si[j];                             \
            sr[j] = x.x * a_ - x.y * b_ + y.x * pr - y.y * pi;        \
            si[j] = x.x * b_ + x.y * a_ + y.x * pi + y.y * pr;        \
        }                                                             \
    }

    // involutive ownership transpose: swap tid[9:6] <-> j[4:1] via LDS.
    // j = (s<<1)|q; stride-17 planes -> 2-way bank aliasing only (free).
#define TRANSPOSE()                                                  \
    {                                                                \
        const int lane6 = tid & 63;                                  \
        const int hi4   = tid >> 6;                                  \
        _Pragma("unroll")                                            \
        for (int q = 0; q < 2; ++q) {                                \
            __syncthreads();                                         \
            _Pragma("unroll")                                        \
            for (int s = 0; s < 16; ++s) {                           \
                ldsr[tid * 17 + s] = sr[s * 2 + q];                  \
                ldsi[tid * 17 + s] = si[s * 2 + q];                  \
            }                                                        \
            __syncthreads();                                         \
            _Pragma("unroll")                                        \
            for (int s = 0; s < 16; ++s) {                           \
                const int a_ = ((s << 6) | lane6) * 17 + hi4;        \
                sr[s * 2 + q] = ldsr[a_];                            \
                si[s * 2 + q] = ldsi[a_];                            \
            }                                                        \
        }                                                            \
    }

    // ---- layer 0 (analytic, in TRANSPOSED mapping) ----
    // transposed bits: wire0:h, wire1:j4, wire2:j3, wire3:j2, wire4:j1, wire15:j0,
    // wire5..10: tid5..tid0, wire11..14: tid9..tid6.
    {
        float2 P = make_float2(1.f, 0.f);
        {
            LOADU(0, 0);
            P = cmul2(P, h ? u10 : u00);
        }
#pragma unroll
        for (int w = 5; w <= 10; ++w) {
            LOADU(0, w);
            int bit = (tid >> (10 - w)) & 1;
            P = cmul2(P, bit ? u10 : u00);
        }
#pragma unroll
        for (int w = 11; w <= 14; ++w) {
            LOADU(0, w);
            int bit = (tid >> (20 - w)) & 1;
            P = cmul2(P, bit ? u10 : u00);
        }
        float2 fA0[3], fA1[3];  // wires 1,2,3 <- j4,j3,j2
        float2 fB0[2], fB1[2];  // wires 4,15 <- j1,j0
#pragma unroll
        for (int i = 0; i < 3; ++i) {
            LOADU(0, 1 + i);
            fA0[i] = u00; fA1[i] = u10;
        }
        {
            LOADU(0, 4);
            fB0[0] = u00; fB1[0] = u10;
        }
        {
            LOADU(0, 15);
            fB0[1] = u00; fB1[1] = u10;
        }
        float2 A[8], Bt[4];
#pragma unroll
        for (int a = 0; a < 8; ++a) {
            float2 x = (a & 4) ? fA1[0] : fA0[0];
            x = cmul2(x, (a & 2) ? fA1[1] : fA0[1]);
            x = cmul2(x, (a & 1) ? fA1[2] : fA0[2]);
            A[a] = cmul2(P, x);
        }
#pragma unroll
        for (int b2 = 0; b2 < 4; ++b2) {
            float2 y = (b2 & 2) ? fB1[0] : fB0[0];
            y = cmul2(y, (b2 & 1) ? fB1[1] : fB0[1]);
            Bt[b2] = y;
        }
#pragma unroll
        for (int j = 0; j < 32; ++j) {
            float2 a = cmul2(A[j >> 2], Bt[j & 3]);
            sr[j] = a.x;
            si[j] = a.y;
        }
    }
    // R1(layer 1): transposed reg gate on j4 (wire1), cond wire0 = h  [CN(0,1)]
    REG_GATE(1, 1, 4, h);
    TRANSPOSE();  // -> normal mapping

    // ---- layers 1..9 ----
#pragma unroll 1
    for (int L = 1; L < NL; ++L) {
        float2* bufp = (L & 1) ? buf0 : buf1;
        // store own half (state = post-R1(L)), normal mapping
        {
            float4* wb = (float4*)(bufp + (((size_t)bb << 16) | ((size_t)h << 15) |
                                           ((size_t)tid << 5)));
#pragma unroll
            for (int k = 0; k < 16; ++k)
                wb[k] = make_float4(sr[2 * k], si[2 * k], sr[2 * k + 1], si[2 * k + 1]);
        }
        grid.sync();
        // load partner half + R0(L): co=U[h][h], cp=U[h][1-h], cond j0^j1 [CN(15,0)]
        {
            const float4* rb = (const float4*)(bufp + (((size_t)bb << 16) |
                                                       ((size_t)(1 - h) << 15) |
                                                       ((size_t)tid << 5)));
            LOADU(L, 0);
            float2 co = h ? u11 : u00;
            float2 cp = h ? u10 : u01;
#pragma unroll
            for (int k = 0; k < 16; ++k) {
                float4 v = rb[k];
                {
                    const int j = 2 * k;
                    const bool c = ((j ^ (j >> 1)) & 1) != 0;
                    float2 x = c ? cp : co, y = c ? co : cp;
                    float a_ = sr[j], b_ = si[j];
                    sr[j] = x.x * a_ - x.y * b_ + y.x * v.x - y.y * v.y;
                    si[j] = x.x * b_ + x.y * a_ + y.x * v.y + y.y * v.x;
                }
                {
                    const int j = 2 * k + 1;
                    const bool c = ((j ^ (j >> 1)) & 1) != 0;
                    float2 x = c ? cp : co, y = c ? co : cp;
                    float a_ = sr[j], b_ = si[j];
                    sr[j] = x.x * a_ - x.y * b_ + y.x * v.z - y.y * v.w;
                    si[j] = x.x * b_ + x.y * a_ + y.x * v.w + y.y * v.z;
                }
            }
        }
        // normal mapping: wire15=j0, wire14=j1
        REG_GATE(L, 15, 0, (jA >> 1) & 1);  // R15, cond wire14   [CN(14,15)]
        REG_GATE(L, 14, 1, 0);              // R14
        TRANSPOSE();  // -> transposed
        REG_GATE(L, 3, 2, (jA >> 3) & 1);   // R3, cond wire2=j3' [CN(2,3)]
        REG_GATE(L, 2, 3, 0);               // R2
        SHFL_GATE_J(L, 5, 32, 5, 1);        // R5, cond wire4=j1' [CN(4,5)]
        REG_GATE(L, 4, 1, 0);               // R4 (reg in transposed)
        SHFL_GATE(L, 7, 8, 3, (tid >> 4) & 1);  // R7, cond wire6  [CN(6,7)]
        SHFL_GATE(L, 6, 16, 4, 0);              // R6
        SHFL_GATE(L, 9, 2, 1, (tid >> 2) & 1);  // R9, cond wire8  [CN(8,9)]
        SHFL_GATE(L, 8, 4, 2, 0);               // R8
        if (L + 1 < NL) {
            REG_GATE(L + 1, 1, 4, h);       // R1(L+1), cond wire0=h [CN(0,1)]
        }
        TRANSPOSE();  // -> normal
        REG_GATE(L, 11, 4, tid & 1);        // R11, cond wire10=tid0 [CN(10,11)]
        SHFL_GATE(L, 10, 1, 0, 0);          // R10
        REG_GATE(L, 13, 2, (jA >> 3) & 1);  // R13, cond wire12=j3   [CN(12,13)]
        REG_GATE(L, 12, 3, 0);              // R12
    }

    // ---- probabilities ----
    {
        float4* o4 = (float4*)(out + (((size_t)bb << 16) | ((size_t)h << 15) |
                                      ((size_t)tid << 5)));
#pragma unroll
        for (int k = 0; k < 8; ++k) {
            float4 v;
            v.x = sr[4 * k + 0] * sr[4 * k + 0] + si[4 * k + 0] * si[4 * k + 0];
            v.y = sr[4 * k + 1] * sr[4 * k + 1] + si[4 * k + 1] * si[4 * k + 1];
            v.z = sr[4 * k + 2] * sr[4 * k + 2] + si[4 * k + 2] * si[4 * k + 2];
            v.w = sr[4 * k + 3] * sr[4 * k + 3] + si[4 * k + 3] * si[4 * k + 3];
            o4[k] = v;
        }
    }
#undef LOADU
#undef REG_GATE
#undef SHFL_GATE
#undef SHFL_GATE_J
#undef TRANSPOSE
}

extern "C" void kernel_launch(void* const* d_in, const int* in_sizes, int n_in,
                              void* d_out, int out_size, void* d_ws, size_t ws_size,
                              hipStream_t stream) {
    const float* params = (const float*)d_in[0];
    float* out = (float*)d_out;
    char* w = (char*)d_ws;
    float2* buf0 = (float2*)w;                   // 64 MiB
    float2* buf1 = (float2*)(w + (1ULL << 26));  // 64 MiB
    float4* cf   = (float4*)(w + (1ULL << 27));  // 320 KiB gate coefficients

    coef_kernel<<<80, 256, 0, stream>>>(params, cf);

    void* args[] = {(void*)&cf, (void*)&buf0, (void*)&buf1, (void*)&out};
    hipLaunchCooperativeKernel((const void*)vqc_coop, dim3(256), dim3(1024),
                               args, 0, stream);
}

// Round 7
// 74.016 us; speedup vs baseline: 187.0831x; 14.5564x over previous
//
#include <hip/hip_runtime.h>

// VQC 16-wire / 10-layer — EXACT tensor-product factorization.
//
// _pairs(16) = (0,1),(2,3),...,(14,15),(15,0): the entanglement graph has 7
// connected components, constant across layers:
//   C0 = {0,1,14,15} (4-qubit: edges 0-1, 14-15, 15-0)
//   Ck = {2k, 2k+1} for k=1..6 (2-qubit)
// No gate couples components => final state = tensor product, and
//   out[m] = p4[x0 x1 x14 x15] * prod_k p2_k[x_{2k} x_{2k+1}]
// (wire w <-> bit 15-w of amp index m).
//
// Kernel 1: one thread per (batch, component) simulates the tiny circuit
// through all 10 layers literally (CNOTs in reference order, then rotations)
// and writes probability factors.
// Kernel 2: memory-bound outer-product expansion, 33.5 MB coalesced write.

#define NB 128
#define NL 10

// U = RZ(tz) RY(ty) RX(tx);  u10 = -conj(u01), u11 = conj(u00).
__device__ __forceinline__ void getU(const float* __restrict__ p,
                                     float& u00r, float& u00i,
                                     float& u01r, float& u01i) {
    float sx, cx, sy, cy, sz, cz;
    sincosf(0.5f * p[0], &sx, &cx);
    sincosf(0.5f * p[1], &sy, &cy);
    sincosf(0.5f * p[2], &sz, &cz);
    u00r =  cz * cy * cx + sz * sy * sx;
    u00i =  cz * sy * sx - sz * cy * cx;
    u01r = -cz * sy * cx - sz * cy * sx;
    u01i = -cz * cy * sx + sz * sy * cx;
}

// single-qubit rotation on bit-mask M of an N-dim register-resident state
template <int N, int M>
__device__ __forceinline__ void rotN(float (&vr)[N], float (&vi)[N],
                                     float u00r, float u00i,
                                     float u01r, float u01i) {
#pragma unroll
    for (int i = 0; i < N; ++i) {
        if ((i & M) == 0) {
            const int lo = i, hi = i | M;
            float ar = vr[lo], ai = vi[lo], br = vr[hi], bi = vi[hi];
            vr[lo] =  u00r * ar - u00i * ai + u01r * br - u01i * bi;
            vi[lo] =  u00r * ai + u00i * ar + u01r * bi + u01i * br;
            vr[hi] = -u01r * ar - u01i * ai + u00r * br + u00i * bi;
            vi[hi] = -u01r * ai + u01i * ar + u00r * bi - u00i * br;
        }
    }
}

// fac layout per batch (64 floats): [0..15] p4 (idx = x0<<3|x1<<2|x14<<1|x15),
// [16+4k .. 16+4k+3] p2_k (idx = x_{2k+2}<<1 | x_{2k+3}), k=0..5.
__global__ __launch_bounds__(256, 4) void factor_kernel(const float* __restrict__ params,
                                                        float* __restrict__ fac) {
    const int gid = blockIdx.x * 256 + threadIdx.x;
    if (gid < NB) {
        // ---- 4-qubit component {0,1,14,15}; basis = x0<<3|x1<<2|x14<<1|x15 ----
        const int b = gid;
        const float* pb = params + b * (48 * NL);
        float vr[16], vi[16];
#pragma unroll
        for (int i = 0; i < 16; ++i) { vr[i] = 0.f; vi[i] = 0.f; }
        vr[0] = 1.f;
#pragma unroll 1
        for (int L = 0; L < NL; ++L) {
            const float* pl = pb + L * 48;
            // CN(0,1): x0=1 (bit3) flips x1 (bit2): swap (8+u, 12+u)
#pragma unroll
            for (int u = 0; u < 4; ++u) {
                const int a = 8 + u, c = 12 + u;
                float tr = vr[a], ti = vi[a];
                vr[a] = vr[c]; vi[a] = vi[c]; vr[c] = tr; vi[c] = ti;
            }
            // CN(14,15): x14=1 (bit1) flips x15 (bit0): swap (4u+2, 4u+3)
#pragma unroll
            for (int u = 0; u < 4; ++u) {
                const int a = 4 * u + 2, c = 4 * u + 3;
                float tr = vr[a], ti = vi[a];
                vr[a] = vr[c]; vi[a] = vi[c]; vr[c] = tr; vi[c] = ti;
            }
            // CN(15,0): x15=1 (bit0) flips x0 (bit3): swap (2u+1, 2u+9)
#pragma unroll
            for (int u = 0; u < 4; ++u) {
                const int a = 2 * u + 1, c = a + 8;
                float tr = vr[a], ti = vi[a];
                vr[a] = vr[c]; vi[a] = vi[c]; vr[c] = tr; vi[c] = ti;
            }
            float u00r, u00i, u01r, u01i;
            getU(pl + 0,  u00r, u00i, u01r, u01i);  // R0  -> bit3
            rotN<16, 8>(vr, vi, u00r, u00i, u01r, u01i);
            getU(pl + 3,  u00r, u00i, u01r, u01i);  // R1  -> bit2
            rotN<16, 4>(vr, vi, u00r, u00i, u01r, u01i);
            getU(pl + 42, u00r, u00i, u01r, u01i);  // R14 -> bit1
            rotN<16, 2>(vr, vi, u00r, u00i, u01r, u01i);
            getU(pl + 45, u00r, u00i, u01r, u01i);  // R15 -> bit0
            rotN<16, 1>(vr, vi, u00r, u00i, u01r, u01i);
        }
#pragma unroll
        for (int i = 0; i < 16; ++i)
            fac[b * 64 + i] = vr[i] * vr[i] + vi[i] * vi[i];
    } else if (gid < NB + NB * 6) {
        // ---- 2-qubit component (c, c+1), c = 2k+2; basis = x_c<<1 | x_{c+1} ----
        const int idx = gid - NB;
        const int b = idx / 6, k = idx % 6;
        const float* pb = params + b * (48 * NL) + (2 * k + 2) * 3;
        float vr[4], vi[4];
        vr[0] = 1.f; vr[1] = vr[2] = vr[3] = 0.f;
        vi[0] = vi[1] = vi[2] = vi[3] = 0.f;
#pragma unroll 1
        for (int L = 0; L < NL; ++L) {
            const float* pl = pb + L * 48;
            // CN(c,c+1): x_c=1 flips x_{c+1}: swap v[2]<->v[3]
            {
                float tr = vr[2], ti = vi[2];
                vr[2] = vr[3]; vi[2] = vi[3]; vr[3] = tr; vi[3] = ti;
            }
            float u00r, u00i, u01r, u01i;
            getU(pl + 0, u00r, u00i, u01r, u01i);   // R_c   -> bit1
            rotN<4, 2>(vr, vi, u00r, u00i, u01r, u01i);
            getU(pl + 3, u00r, u00i, u01r, u01i);   // R_c+1 -> bit0
            rotN<4, 1>(vr, vi, u00r, u00i, u01r, u01i);
        }
#pragma unroll
        for (int i = 0; i < 4; ++i)
            fac[b * 64 + 16 + k * 4 + i] = vr[i] * vr[i] + vi[i] * vi[i];
    }
}

// 512 blocks x 256 threads: block = (batch bb, q = m[15:14]); thread t owns
// m[13:6]; inner 64 values j = m[5:0]. out[m] = f_outer(o) * g[j].
//   o = m[15:6] = q<<8 | t
//   f_outer = p2_0[m13:12] * p2_1[m11:10] * p2_2[m9:8] * p2_3[m7:6]
//   g[j]    = p2_4[j>>4] * p2_5[(j>>2)&3] * p4[q<<2 | (j&3)]   (x14,x15 = m1,m0)
__global__ __launch_bounds__(256, 8) void expand_kernel(const float* __restrict__ fac,
                                                        float* __restrict__ out) {
    const int bb = blockIdx.x >> 2;
    const int q  = blockIdx.x & 3;
    const int t  = threadIdx.x;
    __shared__ float p2s[6][4];
    __shared__ float g[64];
    if (t < 24) p2s[t >> 2][t & 3] = fac[bb * 64 + 16 + t];
    __syncthreads();
    if (t < 64)
        g[t] = p2s[4][(t >> 4) & 3] * p2s[5][(t >> 2) & 3] *
               fac[bb * 64 + ((q << 2) | (t & 3))];
    __syncthreads();
    const int o = (q << 8) | t;
    const float f = p2s[0][(o >> 6) & 3] * p2s[1][(o >> 4) & 3] *
                    p2s[2][(o >> 2) & 3] * p2s[3][o & 3];
    float4* o4 = (float4*)(out + ((size_t)bb << 16) + ((size_t)o << 6));
#pragma unroll
    for (int j4 = 0; j4 < 16; ++j4) {
        float4 v;
        v.x = f * g[j4 * 4 + 0];
        v.y = f * g[j4 * 4 + 1];
        v.z = f * g[j4 * 4 + 2];
        v.w = f * g[j4 * 4 + 3];
        o4[j4] = v;
    }
}

extern "C" void kernel_launch(void* const* d_in, const int* in_sizes, int n_in,
                              void* d_out, int out_size, void* d_ws, size_t ws_size,
                              hipStream_t stream) {
    const float* params = (const float*)d_in[0];
    float* out = (float*)d_out;
    float* fac = (float*)d_ws;  // 128 * 64 floats = 32 KiB

    factor_kernel<<<4, 256, 0, stream>>>(params, fac);   // 896 live threads
    expand_kernel<<<512, 256, 0, stream>>>(fac, out);    // 33.5 MB write
}

// Round 8
// 38.026 us; speedup vs baseline: 364.1431x; 1.9464x over previous
//
#include <hip/hip_runtime.h>

// VQC 16-wire / 10-layer — EXACT tensor-product factorization, single kernel.
//
// _pairs(16) couples only {0,1,14,15} (edges 0-1, 14-15, 15-0) and the six
// pairs {2k,2k+1}, k=1..6. Components never interact =>
//   out[m] = p4[x0 x1 x14 x15] * prod_k p2_k[x_{2k} x_{2k+1}]
// (wire w <-> bit 15-w of amp index m). Verified round 7 (absmax 3.05e-5).
//
// One kernel, 512 blocks x 256 threads; block = (batch bb, quadrant q=m[15:14]).
// Phase A: threads 0..159 compute the batch's 160 gate-U's in parallel (kills
//          the serial-sincosf chain that dominated round 7's factor_kernel).
// Phase B: threads 0..6 run the tiny 10-layer component sims from LDS U's
//          (pure FMA, fully unrolled; swaps are compile-time renames).
// Phase C: outer-product expansion, 33.5 MB coalesced write (the roofline).

#define NB 128
#define NL 10

// U = RZ(tz) RY(ty) RX(tx);  u10 = -conj(u01), u11 = conj(u00).
__device__ __forceinline__ void getU(const float* __restrict__ p,
                                     float& u00r, float& u00i,
                                     float& u01r, float& u01i) {
    float sx, cx, sy, cy, sz, cz;
    sincosf(0.5f * p[0], &sx, &cx);
    sincosf(0.5f * p[1], &sy, &cy);
    sincosf(0.5f * p[2], &sz, &cz);
    u00r =  cz * cy * cx + sz * sy * sx;
    u00i =  cz * sy * sx - sz * cy * cx;
    u01r = -cz * sy * cx - sz * cy * sx;
    u01i = -cz * cy * sx + sz * sy * cx;
}

// single-qubit rotation on bit-mask M of an N-dim register-resident state
template <int N, int M>
__device__ __forceinline__ void rotN(float (&vr)[N], float (&vi)[N], float4 U) {
    const float u00r = U.x, u00i = U.y, u01r = U.z, u01i = U.w;
#pragma unroll
    for (int i = 0; i < N; ++i) {
        if ((i & M) == 0) {
            const int lo = i, hi = i | M;
            float ar = vr[lo], ai = vi[lo], br = vr[hi], bi = vi[hi];
            vr[lo] =  u00r * ar - u00i * ai + u01r * br - u01i * bi;
            vi[lo] =  u00r * ai + u00i * ar + u01r * bi + u01i * br;
            vr[hi] = -u01r * ar - u01i * ai + u00r * br + u00i * bi;
            vi[hi] = -u01r * ai + u01i * ar + u00r * bi - u00i * br;
        }
    }
}

__global__ __launch_bounds__(256, 2) void vqc_fused(const float* __restrict__ params,
                                                    float* __restrict__ out) {
    const int bb = blockIdx.x >> 2;   // batch
    const int q  = blockIdx.x & 3;    // m[15:14] quadrant
    const int t  = threadIdx.x;

    __shared__ float4 Us[NL * 16];    // per-gate U (u00r,u00i,u01r,u01i)
    __shared__ float  p4s[16];        // |amp|^2 of 4-qubit comp {0,1,14,15}
    __shared__ float  p2s[6][4];      // |amp|^2 of pair comps (2k+2, 2k+3)
    __shared__ float  g[64];          // inner-64 expansion factors

    // ---- Phase A: all 160 gate matrices in parallel ----
    if (t < NL * 16) {
        const int L = t >> 4, w = t & 15;
        const float* p = params + bb * (48 * NL) + L * 48 + w * 3;
        float a, b, c, d;
        getU(p, a, b, c, d);
        Us[t] = make_float4(a, b, c, d);
    }
    __syncthreads();

    // ---- Phase B: tiny component sims (threads 0..6) ----
    if (t == 0) {
        // 4-qubit {0,1,14,15}; basis = x0<<3 | x1<<2 | x14<<1 | x15
        float vr[16], vi[16];
#pragma unroll
        for (int i = 0; i < 16; ++i) { vr[i] = 0.f; vi[i] = 0.f; }
        vr[0] = 1.f;
#pragma unroll
        for (int L = 0; L < NL; ++L) {
            // CN(0,1): bit3 controls bit2: swap (8+u, 12+u)
#pragma unroll
            for (int u = 0; u < 4; ++u) {
                const int a = 8 + u, c = 12 + u;
                float tr = vr[a], ti = vi[a];
                vr[a] = vr[c]; vi[a] = vi[c]; vr[c] = tr; vi[c] = ti;
            }
            // CN(14,15): bit1 controls bit0: swap (4u+2, 4u+3)
#pragma unroll
            for (int u = 0; u < 4; ++u) {
                const int a = 4 * u + 2, c = a + 1;
                float tr = vr[a], ti = vi[a];
                vr[a] = vr[c]; vi[a] = vi[c]; vr[c] = tr; vi[c] = ti;
            }
            // CN(15,0): bit0 controls bit3: swap (2u+1, 2u+9)
#pragma unroll
            for (int u = 0; u < 4; ++u) {
                const int a = 2 * u + 1, c = a + 8;
                float tr = vr[a], ti = vi[a];
                vr[a] = vr[c]; vi[a] = vi[c]; vr[c] = tr; vi[c] = ti;
            }
            rotN<16, 8>(vr, vi, Us[L * 16 + 0]);   // R0  -> bit3
            rotN<16, 4>(vr, vi, Us[L * 16 + 1]);   // R1  -> bit2
            rotN<16, 2>(vr, vi, Us[L * 16 + 14]);  // R14 -> bit1
            rotN<16, 1>(vr, vi, Us[L * 16 + 15]);  // R15 -> bit0
        }
#pragma unroll
        for (int i = 0; i < 16; ++i) p4s[i] = vr[i] * vr[i] + vi[i] * vi[i];
    } else if (t <= 6) {
        // pair component (c, c+1), c = 2k+2; basis = x_c<<1 | x_{c+1}
        const int k = t - 1, c = 2 * k + 2;
        float vr[4], vi[4];
        vr[0] = 1.f; vr[1] = vr[2] = vr[3] = 0.f;
        vi[0] = vi[1] = vi[2] = vi[3] = 0.f;
#pragma unroll
        for (int L = 0; L < NL; ++L) {
            // CN(c,c+1): swap v[2] <-> v[3]
            float tr = vr[2], ti = vi[2];
            vr[2] = vr[3]; vi[2] = vi[3]; vr[3] = tr; vi[3] = ti;
            rotN<4, 2>(vr, vi, Us[L * 16 + c]);      // R_c   -> bit1
            rotN<4, 1>(vr, vi, Us[L * 16 + c + 1]);  // R_c+1 -> bit0
        }
#pragma unroll
        for (int i = 0; i < 4; ++i)
            p2s[k][i] = vr[i] * vr[i] + vi[i] * vi[i];
    }
    __syncthreads();

    // ---- Phase C: expansion. o = m[15:6] = q<<8 | t; j = m[5:0]. ----
    // g[j] = p2_4[m5:4] * p2_5[m3:2] * p4[q<<2 | m1:0]
    if (t < 64)
        g[t] = p2s[4][(t >> 4) & 3] * p2s[5][(t >> 2) & 3] *
               p4s[(q << 2) | (t & 3)];
    __syncthreads();
    // f = p2_0[m13:12] * p2_1[m11:10] * p2_2[m9:8] * p2_3[m7:6]  (t = o[7:0])
    const float f = p2s[0][(t >> 6) & 3] * p2s[1][(t >> 4) & 3] *
                    p2s[2][(t >> 2) & 3] * p2s[3][t & 3];
    const int o = (q << 8) | t;
    float4* o4 = (float4*)(out + ((size_t)bb << 16) + ((size_t)o << 6));
#pragma unroll
    for (int j4 = 0; j4 < 16; ++j4) {
        float4 v;
        v.x = f * g[j4 * 4 + 0];
        v.y = f * g[j4 * 4 + 1];
        v.z = f * g[j4 * 4 + 2];
        v.w = f * g[j4 * 4 + 3];
        o4[j4] = v;
    }
}

extern "C" void kernel_launch(void* const* d_in, const int* in_sizes, int n_in,
                              void* d_out, int out_size, void* d_ws, size_t ws_size,
                              hipStream_t stream) {
    const float* params = (const float*)d_in[0];
    float* out = (float*)d_out;
    vqc_fused<<<512, 256, 0, stream>>>(params, out);
}

// Round 9
// 17.233 us; speedup vs baseline: 803.5187x; 2.2066x over previous
//
#include <hip/hip_runtime.h>

// VQC 16-wire / 10-layer — EXACT tensor-product factorization, single kernel.
//
// _pairs(16) couples only {0,1,14,15} (edges 0-1, 14-15, 15-0) and the six
// pairs {2k,2k+1}, k=1..6. Components never interact =>
//   out[m] = p4[x0 x1 x14 x15] * prod_k p2_k[x_{2k} x_{2k+1}]
// (wire w <-> bit 15-w of amp index m). Verified rounds 7-8 (absmax 3.05e-5).
//
// One kernel, 512 blocks x 256 threads; block = (batch bb, quadrant q=m[15:14]).
// Phase A: threads 0..159 compute the batch's 160 gate-U's in parallel.
// Phase B: LANE-PARALLEL component sims on wave 0 (round 8 ran this serially
//          on thread 0: ~9000 1-lane VALU ops ~ 8 us of latency). Lanes 0..15
//          hold the 4-qubit comp (1 complex amp/lane); lanes 16..39 hold six
//          2-qubit comps (4 lanes each). CNOT = __shfl permutation; rotation =
//          __shfl pair exchange + per-lane coeff select. 7 steps/layer.
// Phase C: outer-product expansion; float4 slot (i<<8)|t so each wave store
//          is 1 KB contiguous (round 8 scattered 16 B/lane at 256 B stride).

#define NB 128
#define NL 10

// U = RZ(tz) RY(ty) RX(tx);  u10 = -conj(u01), u11 = conj(u00).
__device__ __forceinline__ void getU(const float* __restrict__ p,
                                     float& u00r, float& u00i,
                                     float& u01r, float& u01i) {
    float sx, cx, sy, cy, sz, cz;
    sincosf(0.5f * p[0], &sx, &cx);
    sincosf(0.5f * p[1], &sy, &cy);
    sincosf(0.5f * p[2], &sz, &cz);
    u00r =  cz * cy * cx + sz * sy * sx;
    u00i =  cz * sy * sx - sz * cy * cx;
    u01r = -cz * sy * cx - sz * cy * sx;
    u01i = -cz * cy * sx + sz * sy * cx;
}

__global__ __launch_bounds__(256, 8) void vqc_fused(const float* __restrict__ params,
                                                    float* __restrict__ out) {
    const int bb = blockIdx.x >> 2;   // batch
    const int q  = blockIdx.x & 3;    // m[15:14] quadrant
    const int t  = threadIdx.x;

    __shared__ float4 Us[NL * 16];    // per-gate U (u00r,u00i,u01r,u01i)
    __shared__ float  p4s[16];        // |amp|^2 of 4-qubit comp {0,1,14,15}
    __shared__ float  p2s[6][4];      // |amp|^2 of pair comps (2k+2, 2k+3)
    __shared__ float  g[64];          // inner-64 factors (j = m[5:0])
    __shared__ float  fi_s[16];       // outer factors   (i = m[13:10])

    // ---- Phase A: all 160 gate matrices in parallel ----
    if (t < NL * 16) {
        const int L = t >> 4, w = t & 15;
        const float* p = params + bb * (48 * NL) + L * 48 + w * 3;
        float a, b, c, d;
        getU(p, a, b, c, d);
        Us[t] = make_float4(a, b, c, d);
    }
    __syncthreads();

    // ---- Phase B: lane-parallel component sims (wave 0 only) ----
    if (t < 64) {
        const bool isC0   = (t < 16);
        const bool isPair = (t >= 16 && t < 40);
        const int  k      = isPair ? ((t - 16) >> 2) : 0;   // pair comp id
        const int  lb     = isC0 ? t : (t & 3);             // local basis idx
        // CNOT permutation source lanes (involutions; self for idle lanes)
        int p1 = t, p2 = t, p3 = t;
        if (isC0) {
            p1 = t ^ ((t & 8) >> 1);   // CN(0,1):  bit3 controls bit2
            p2 = t ^ ((t & 2) >> 1);   // CN(14,15): bit1 controls bit0
            p3 = t ^ ((t & 1) << 3);   // CN(15,0): bit0 controls bit3
        } else if (isPair) {
            p1 = (t & ~3) | (lb ^ ((lb & 2) >> 1));  // CN(c,c+1)
        }
        // rotation steps: local mask (0 = identity) and wire id
        int m4 = 0, m5 = 0, m6 = 0, m7 = 0;
        int w4 = 0, w5 = 0, w6 = 0, w7 = 0;
        if (isC0)      { m4 = 8; w4 = 0;          m5 = 4; w5 = 1;
                         m6 = 2; w6 = 14;         m7 = 1; w7 = 15; }
        else if (isPair) { m4 = 2; w4 = 2 * k + 2; m5 = 1; w5 = 2 * k + 3; }

        float vr = (lb == 0 && (isC0 || isPair)) ? 1.f : 0.f;
        float vi = 0.f;

#define PERM(SRC)                         \
    do {                                  \
        vr = __shfl(vr, (SRC), 64);       \
        vi = __shfl(vi, (SRC), 64);       \
    } while (0)
#define ROT(M, W)                                                   \
    do {                                                            \
        const int m_ = (M);                                         \
        float4 U = Us[L * 16 + (W)];                                \
        float prr = __shfl(vr, t ^ m_, 64);                         \
        float pri = __shfl(vi, t ^ m_, 64);                         \
        const bool act = m_ != 0;                                   \
        const bool up  = (lb & m_) == 0;                            \
        float cor = act ? U.x : 1.f;                                \
        float coi = act ? (up ? U.y : -U.y) : 0.f;                  \
        float cpr = act ? (up ? U.z : -U.z) : 0.f;                  \
        float cpi = act ? U.w : 0.f;                                \
        float nr = cor * vr - coi * vi + cpr * prr - cpi * pri;     \
        float ni = cor * vi + coi * vr + cpr * pri + cpi * prr;     \
        vr = nr;                                                    \
        vi = ni;                                                    \
    } while (0)

#pragma unroll 1
        for (int L = 0; L < NL; ++L) {
            PERM(p1);
            PERM(p2);
            PERM(p3);
            ROT(m4, w4);
            ROT(m5, w5);
            ROT(m6, w6);
            ROT(m7, w7);
        }
#undef PERM
#undef ROT
        const float pr = vr * vr + vi * vi;
        if (isC0) p4s[t] = pr;
        else if (isPair) p2s[k][lb] = pr;
    }
    __syncthreads();

    // ---- Phase C: expansion. local float idx = i<<10 | t<<2 | e. ----
    if (t < 64)
        g[t] = p2s[4][(t >> 4) & 3] * p2s[5][(t >> 2) & 3] *
               p4s[(q << 2) | (t & 3)];
    if (t < 16) fi_s[t] = p2s[0][t >> 2] * p2s[1][t & 3];
    __syncthreads();

    const float ft = p2s[2][t >> 6] * p2s[3][(t >> 4) & 3];
    const float4 g4 = *(const float4*)&g[(t & 15) << 2];
    const float g0 = ft * g4.x, g1 = ft * g4.y, g2 = ft * g4.z, g3 = ft * g4.w;
    float4* ob = (float4*)(out + (((size_t)bb << 16) | ((size_t)q << 14)));
#pragma unroll
    for (int i = 0; i < 16; ++i) {
        const float f = fi_s[i];
        ob[(i << 8) | t] = make_float4(f * g0, f * g1, f * g2, f * g3);
    }
}

extern "C" void kernel_launch(void* const* d_in, const int* in_sizes, int n_in,
                              void* d_out, int out_size, void* d_ws, size_t ws_size,
                              hipStream_t stream) {
    const float* params = (const float*)d_in[0];
    float* out = (float*)d_out;
    vqc_fused<<<512, 256, 0, stream>>>(params, out);
}